// Round 5
// baseline (364.491 us; speedup 1.0000x reference)
//
#include <hip/hip_runtime.h>
#include <stdint.h>

// Problem constants
#define NJ 192                    // N1
#define OUT_HALF 12582912         // B*HN*N1 = 4096*16*192

// Per-block geometry: 32 rows (2 batches x 16 heads), 512 threads = 8 waves
// = 2 m-tiles x 4 N-quarters. 2048 blocks. LDS 70656 B -> 2 blocks/CU, so
// one block's MFMA phases overlap the other's HBM scatter/gather phases.
#define XS 520                    // X tile (bf16): 32 x 520
#define WSS 40                    // W chunk (bf16): 256 x 40 (BK=32 + 16B pad)
#define HS 264                    // H tile (bf16): 32 x 264
#define OS 516                    // O tile (f32):  32 x 516 (overlay)

typedef __attribute__((ext_vector_type(4))) float f32x4;
typedef __attribute__((ext_vector_type(8))) short bf16x8;

__device__ __forceinline__ float bf2f(short u) {
    union { float f; uint32_t i; } c;
    c.i = ((uint32_t)(uint16_t)u) << 16;
    return c.f;
}
__device__ __forceinline__ short f2bf(float f) {
    union { float f; uint32_t i; } c;
    c.f = f;
    uint32_t x = c.i;
    uint32_t r = (x + 0x7fffu + ((x >> 16) & 1u)) >> 16;   // RNE
    return (short)(uint16_t)r;
}

// ---------------------------------------------------------------------------
// Pre-kernel: convert W1/W2 f32 -> bf16, packed chunk-major into d_ws.
// Both packed as 16 chunks x 256 rows x 32 k (8-elem blocks: chunk*1024+row*4+j).
//   P1 (ws+0):      chunk c<16:       row<256 of W1, k = c*32 + j*8 + e
//   P2 (ws+131072): chunk t=h*8+c<16: row r<256 -> W2 row h*256+r, k = c*32+j*8+e
// ---------------------------------------------------------------------------
__global__ __launch_bounds__(256)
void pack_weights(const float* __restrict__ W1, const float* __restrict__ W2,
                  short* __restrict__ ws) {
    int id = blockIdx.x * 256 + threadIdx.x;     // 0..32767
    const float* src;
    short* dst;
    if (id < 16384) {              // W1
        int c = id >> 10, w = id & 1023;
        int row = w >> 2, j = w & 3;
        src = W1 + row * 512 + c * 32 + j * 8;
        dst = ws + id * 8;
    } else {                       // W2
        int id2 = id - 16384;
        int c16 = id2 >> 10, w = id2 & 1023;
        int row = w >> 2, j = w & 3;
        int h = c16 >> 3, cc = c16 & 7;
        src = W2 + (h * 256 + row) * 256 + cc * 32 + j * 8;
        dst = ws + 131072 + id2 * 8;
    }
    f32x4 a = *(const f32x4*)src;
    f32x4 b = *(const f32x4*)(src + 4);
    bf16x8 o;
    #pragma unroll
    for (int e = 0; e < 4; ++e) { o[e] = f2bf(a[e]); o[e + 4] = f2bf(b[e]); }
    *(bf16x8*)dst = o;
}

// ---------------------------------------------------------------------------
// Main kernel: fused scatter -> LN -> GEMM1(relu) -> GEMM2(sigmoid) -> gather.
// ---------------------------------------------------------------------------
__global__ __launch_bounds__(512)
void fused_mlp(const float* __restrict__ rgb,
               const float* __restrict__ tir,
               const int*  __restrict__ gidx,
               const float* __restrict__ ln_g,
               const float* __restrict__ ln_b,
               const short* __restrict__ P1,   // packed bf16 W1 chunks
               const float* __restrict__ b1,   // (256)
               const short* __restrict__ P2,   // packed bf16 W2 chunks
               const float* __restrict__ b2,   // (512)
               float* __restrict__ out)        // rgb half then tir half, f32
{
    // 70656-byte arena, manually aliased:
    //   sX (bf16) [0, 33280)  sW (bf16) [33280, 53760)  sH (bf16) [53760, 70656)
    //   sO (f32)  [0, 66048) -- overlay, used only after GEMM2 completes
    __shared__ __attribute__((aligned(16))) char arena[70656];
    short* sX = (short*)arena;
    short* sW = (short*)(arena + 33280);
    short* sH = (short*)(arena + 53760);
    float* sO = (float*)arena;

    const int tid  = threadIdx.x;
    const int blk  = blockIdx.x;
    const int row0 = blk * 32;       // global row = b*16 + h
    const int b0   = blk * 2;
    const int wave = tid >> 6;
    const int lane = tid & 63;
    const int lr   = lane & 15;      // fragment row (A) / col (B,D)
    const int quad = lane >> 4;      // 0..3
    const int mw   = wave & 1;       // m-tile (16 rows)
    const int nw   = wave >> 1;      // N-quarter

    int ivs[12];                     // cached scatter/gather indices

    // ---- Phase 0: zero X, then scatter f32->bf16 through gidx ----
    {
        uint32_t* xz = (uint32_t*)sX;
        for (int i = tid; i < 8320; i += 512) xz[i] = 0u;   // 32*520 shorts
    }
    __syncthreads();
    #pragma unroll
    for (int it = 0; it < 12; ++it) {
        int p = it * 512 + tid;           // 0 .. 32*192-1
        int r = p / NJ;
        int j = p - r * NJ;
        int iv = gidx[(b0 + (r >> 4)) * NJ + j];     // 0..255
        ivs[it] = iv;
        float vr = rgb[row0 * NJ + p];
        float vt = tir[row0 * NJ + p];
        sX[r * XS + iv]       = f2bf(vr);
        sX[r * XS + 256 + iv] = f2bf(vt);
    }
    __syncthreads();

    // ---- Phase 0.5: LayerNorm over 512 per row; 16 threads per row ----
    {
        int r = tid >> 4, sub = tid & 15;
        short* xr = sX + r * XS + sub * 32;
        float s = 0.f, ss = 0.f;
        #pragma unroll
        for (int t = 0; t < 4; ++t) {
            bf16x8 v8 = *(bf16x8*)(xr + t * 8);
            #pragma unroll
            for (int e = 0; e < 8; ++e) { float v = bf2f(v8[e]); s += v; ss += v * v; }
        }
        s  += __shfl_xor(s, 1, 16);  ss += __shfl_xor(ss, 1, 16);
        s  += __shfl_xor(s, 2, 16);  ss += __shfl_xor(ss, 2, 16);
        s  += __shfl_xor(s, 4, 16);  ss += __shfl_xor(ss, 4, 16);
        s  += __shfl_xor(s, 8, 16);  ss += __shfl_xor(ss, 8, 16);
        float mu  = s * (1.f / 512.f);
        float var = ss * (1.f / 512.f) - mu * mu;
        float rs  = rsqrtf(var + 1e-5f);
        const float* gp = ln_g + sub * 32;
        const float* bp = ln_b + sub * 32;
        #pragma unroll
        for (int t = 0; t < 4; ++t) {
            bf16x8 v8 = *(bf16x8*)(xr + t * 8);
            f32x4 g0 = *(const f32x4*)(gp + t * 8);
            f32x4 g1 = *(const f32x4*)(gp + t * 8 + 4);
            f32x4 c0 = *(const f32x4*)(bp + t * 8);
            f32x4 c1 = *(const f32x4*)(bp + t * 8 + 4);
            bf16x8 o8;
            #pragma unroll
            for (int e = 0; e < 4; ++e) {
                o8[e]     = f2bf((bf2f(v8[e])     - mu) * rs * g0[e] + c0[e]);
                o8[e + 4] = f2bf((bf2f(v8[e + 4]) - mu) * rs * g1[e] + c1[e]);
            }
            *(bf16x8*)(xr + t * 8) = o8;
        }
    }
    __syncthreads();

    // ---- Phase 1: H(32x256) = relu(X @ W1^T + b1), K=512 in 16 chunks of 32 ----
    f32x4 acc1[4];
    #pragma unroll
    for (int i = 0; i < 4; ++i) acc1[i] = (f32x4){0.f, 0.f, 0.f, 0.f};

    for (int c = 0; c < 16; ++c) {
        {   // stage chunk: 1024 bf16x8 blocks, 2 per thread
            const short* src = P1 + c * 8192;
            #pragma unroll
            for (int i = 0; i < 2; ++i) {
                int idx = i * 512 + tid;          // 8-elem block index
                int row = idx >> 2, j = idx & 3;
                *(bf16x8*)(sW + row * WSS + j * 8) = *(const bf16x8*)(src + idx * 8);
            }
        }
        __syncthreads();
        bf16x8 a = *(const bf16x8*)(sX + (mw * 16 + lr) * XS + c * 32 + quad * 8);
        #pragma unroll
        for (int i = 0; i < 4; ++i) {
            int nt = nw * 4 + i;
            bf16x8 bfr = *(const bf16x8*)(sW + (nt * 16 + lr) * WSS + quad * 8);
            acc1[i] = __builtin_amdgcn_mfma_f32_16x16x32_bf16(a, bfr, acc1[i], 0, 0, 0);
        }
        __syncthreads();   // sW reused next chunk
    }

    // epilogue 1: bias + relu -> bf16 H in LDS (C/D layout: col=lr, row=quad*4+rr)
    #pragma unroll
    for (int i = 0; i < 4; ++i) {
        int col = (nw * 4 + i) * 16 + lr;
        float bias = b1[col];
        #pragma unroll
        for (int rr = 0; rr < 4; ++rr) {
            int row = mw * 16 + quad * 4 + rr;
            float h = acc1[i][rr] + bias;
            sH[row * HS + col] = f2bf(fmaxf(h, 0.f));
        }
    }
    __syncthreads();

    // ---- Phase 2: O(32x512) = sigmoid(H @ W2^T + b2), K=256, two N-halves ----
    f32x4 acc2[8];
    #pragma unroll
    for (int i = 0; i < 8; ++i) acc2[i] = (f32x4){0.f, 0.f, 0.f, 0.f};

    for (int h = 0; h < 2; ++h) {
        for (int c = 0; c < 8; ++c) {
            {   // stage chunk (rows h*256..h*256+255 of W2, k = c*32..)
                const short* src = P2 + (h * 8 + c) * 8192;
                #pragma unroll
                for (int i = 0; i < 2; ++i) {
                    int idx = i * 512 + tid;
                    int row = idx >> 2, j = idx & 3;
                    *(bf16x8*)(sW + row * WSS + j * 8) = *(const bf16x8*)(src + idx * 8);
                }
            }
            __syncthreads();
            bf16x8 a = *(const bf16x8*)(sH + (mw * 16 + lr) * HS + c * 32 + quad * 8);
            #pragma unroll
            for (int i = 0; i < 4; ++i) {
                int ntl = nw * 4 + i;
                bf16x8 bfr = *(const bf16x8*)(sW + (ntl * 16 + lr) * WSS + quad * 8);
                acc2[h * 4 + i] = __builtin_amdgcn_mfma_f32_16x16x32_bf16(a, bfr, acc2[h * 4 + i], 0, 0, 0);
            }
            __syncthreads();
        }
    }

    // epilogue 2: bias + sigmoid -> f32 O (overlays the arena; X/W/H dead)
    #pragma unroll
    for (int h = 0; h < 2; ++h) {
        #pragma unroll
        for (int i = 0; i < 4; ++i) {
            int col = h * 256 + (nw * 4 + i) * 16 + lr;
            float bias = b2[col];
            #pragma unroll
            for (int rr = 0; rr < 4; ++rr) {
                int row = mw * 16 + quad * 4 + rr;
                float x = acc2[h * 4 + i][rr] + bias;
                float sg = 1.f / (1.f + __expf(-x));
                sO[row * OS + col] = sg;
            }
        }
    }
    __syncthreads();

    // ---- Phase 3: gather through cached indices, store both halves (f32) ----
    #pragma unroll
    for (int it = 0; it < 12; ++it) {
        int p = it * 512 + tid;
        int r = p / NJ;
        int iv = ivs[it];
        out[row0 * NJ + p]            = sO[r * OS + iv];
        out[OUT_HALF + row0 * NJ + p] = sO[r * OS + 256 + iv];
    }
}

extern "C" void kernel_launch(void* const* d_in, const int* in_sizes, int n_in,
                              void* d_out, int out_size, void* d_ws, size_t ws_size,
                              hipStream_t stream) {
    const float* rgb  = (const float*)d_in[0];
    const float* tir  = (const float*)d_in[1];
    const int*   gidx = (const int*)d_in[2];
    const float* ln_g = (const float*)d_in[3];
    const float* ln_b = (const float*)d_in[4];
    const float* W1   = (const float*)d_in[5];
    const float* b1   = (const float*)d_in[6];
    const float* W2   = (const float*)d_in[7];
    const float* b2   = (const float*)d_in[8];
    float* out = (float*)d_out;
    short* wsp = (short*)d_ws;     // needs 512 KB: P1 at 0, P2 at elem 131072

    pack_weights<<<128, 256, 0, stream>>>(W1, W2, wsp);
    fused_mlp<<<2048, 512, 0, stream>>>(rgb, tir, gidx, ln_g, ln_b,
                                        wsp, b1, wsp + 131072, b2, out);
}